// Round 11
// baseline (131.630 us; speedup 1.0000x reference)
//
#include <hip/hip_runtime.h>
#include <hip/hip_fp16.h>

// Problem constants (from reference)
constexpr int BATCH    = 4096;
constexpr int IN_DIM   = 1024;
constexpr int HIDDEN   = 8192;
constexpr int N_LAYERS = 6;
constexpr int OUT_DIM  = 8;
constexpr float INV_TAU = 0.1f;

// Tiling
constexpr int TB   = 16;            // batch rows per workgroup (16 fp8 = uint4)
constexpr int NTH  = 1024;          // threads per block (16 waves)
constexpr int NPT  = HIDDEN / NTH;  // neurons per thread = 8 (all in ONE group)
constexpr int NWAVES = NTH / 64;    // 16

typedef float v2f __attribute__((ext_vector_type(2)));

__device__ __forceinline__ __half2 u2h(unsigned int u) {
    union { unsigned int u; __half2 h; } v; v.u = u; return v.h;
}
__device__ __forceinline__ unsigned int h2u(__half2 h) {
    union { unsigned int u; __half2 h; } v; v.h = h; return v.u;
}
__device__ __forceinline__ uint2 pack4h(float4 v) {
    __half2 lo = __float22half2_rn(make_float2(v.x, v.y));
    __half2 hi = __float22half2_rn(make_float2(v.z, v.w));
    uint2 r; r.x = h2u(lo); r.y = h2u(hi); return r;
}

// ---------------------------------------------------------------------------
// Kernel 1: packed per-neuron records:
//   coefp[l*H+j] = 4 fp16 gate coefs (c0,c1 | c2,c3)
//   idxp [l*H+j] = ia | (ib << 16)
// ---------------------------------------------------------------------------
__global__ void prep_kernel(const float* __restrict__ logic_w,
                            const int* __restrict__ idx0_a,
                            const int* __restrict__ idx0_b,
                            const int* __restrict__ idx_a,
                            const int* __restrict__ idx_b,
                            uint2* __restrict__ coefp,
                            unsigned int* __restrict__ idxp, int n)
{
    int id = blockIdx.x * blockDim.x + threadIdx.x;
    if (id >= n) return;
    const int l = id / HIDDEN;
    const int j = id - l * HIDDEN;

    int ia, ib;
    if (l == 0) { ia = idx0_a[j]; ib = idx0_b[j]; }
    else        { ia = idx_a[(size_t)(l - 1) * HIDDEN + j];
                  ib = idx_b[(size_t)(l - 1) * HIDDEN + j]; }
    idxp[id] = (unsigned int)ia | ((unsigned int)ib << 16);

    const float4* w4 = (const float4*)(logic_w + (size_t)id * 16);
    float4 wa = w4[0], wb = w4[1], wc = w4[2], wd = w4[3];
    float wv[16] = {wa.x, wa.y, wa.z, wa.w, wb.x, wb.y, wb.z, wb.w,
                    wc.x, wc.y, wc.z, wc.w, wd.x, wd.y, wd.z, wd.w};
    float m = wv[0];
#pragma unroll
    for (int i = 1; i < 16; ++i) m = fmaxf(m, wv[i]);
    float e[16];
    float s = 0.f;
#pragma unroll
    for (int i = 0; i < 16; ++i) { e[i] = expf(wv[i] - m); s += e[i]; }
    float inv = 1.f / s;
    const float G0[16] = {0,0,0,0,0,0,0,0, 1,1,1,1,1,1,1,1};
    const float G1[16] = {0,0,1,1,0,0,1,1, -1,-1,0,0,-1,-1,0,0};
    const float G2[16] = {0,0,0,0,1,1,1,1, -1,-1,-1,-1,0,0,0,0};
    const float G3[16] = {0,1,-1,0,-1,0,-2,-1, 1,2,0,1,0,1,-1,0};
    float c0 = 0.f, c1 = 0.f, c2 = 0.f, c3 = 0.f;
#pragma unroll
    for (int i = 0; i < 16; ++i) {
        float p = e[i] * inv;
        c0 = fmaf(p, G0[i], c0);
        c1 = fmaf(p, G1[i], c1);
        c2 = fmaf(p, G2[i], c2);
        c3 = fmaf(p, G3[i], c3);
    }
    coefp[id] = pack4h(make_float4(c0, c1, c2, c3));
}

// gate on ONE dword (4 fp8 rows): convert -> 12 fma -> repack immediately.
// Keeps live f32 temps ~12.
__device__ __forceinline__ unsigned int gate4d(unsigned int a8, unsigned int b8,
                                               float c0, float c1, float c2, float c3)
{
    v2f alo = __builtin_amdgcn_cvt_pk_f32_fp8((int)a8, false);
    v2f ahi = __builtin_amdgcn_cvt_pk_f32_fp8((int)a8, true);
    v2f blo = __builtin_amdgcn_cvt_pk_f32_fp8((int)b8, false);
    v2f bhi = __builtin_amdgcn_cvt_pk_f32_fp8((int)b8, true);
    float r0 = fmaf(blo.x, fmaf(c3, alo.x, c2), fmaf(c1, alo.x, c0));
    float r1 = fmaf(blo.y, fmaf(c3, alo.y, c2), fmaf(c1, alo.y, c0));
    float r2 = fmaf(bhi.x, fmaf(c3, ahi.x, c2), fmaf(c1, ahi.x, c0));
    float r3 = fmaf(bhi.y, fmaf(c3, ahi.y, c2), fmaf(c1, ahi.y, c0));
    int w = __builtin_amdgcn_cvt_pk_fp8_f32(r0, r1, 0, false);
    w     = __builtin_amdgcn_cvt_pk_fp8_f32(r2, r3, w, true);
    return (unsigned int)w;
}

// same, but accumulate 4 f32 results (last layer: no repack)
__device__ __forceinline__ void gate4d_acc(unsigned int a8, unsigned int b8,
                                           float c0, float c1, float c2, float c3,
                                           float* s)
{
    v2f alo = __builtin_amdgcn_cvt_pk_f32_fp8((int)a8, false);
    v2f ahi = __builtin_amdgcn_cvt_pk_f32_fp8((int)a8, true);
    v2f blo = __builtin_amdgcn_cvt_pk_f32_fp8((int)b8, false);
    v2f bhi = __builtin_amdgcn_cvt_pk_f32_fp8((int)b8, true);
    s[0] += fmaf(blo.x, fmaf(c3, alo.x, c2), fmaf(c1, alo.x, c0));
    s[1] += fmaf(blo.y, fmaf(c3, alo.y, c2), fmaf(c1, alo.y, c0));
    s[2] += fmaf(bhi.x, fmaf(c3, ahi.x, c2), fmaf(c1, ahi.x, c0));
    s[3] += fmaf(bhi.y, fmaf(c3, ahi.y, c2), fmaf(c1, ahi.y, c0));
}

__device__ __forceinline__ uint4 gate16(uint4 a, uint4 b, uint2 c) {
    __half2 cp01 = u2h(c.x), cp23 = u2h(c.y);
    float c0 = __low2float(cp01), c1 = __high2float(cp01);
    float c2 = __low2float(cp23), c3 = __high2float(cp23);
    uint4 r;
    r.x = gate4d(a.x, b.x, c0, c1, c2, c3);
    r.y = gate4d(a.y, b.y, c0, c1, c2, c3);
    r.z = gate4d(a.z, b.z, c0, c1, c2, c3);
    r.w = gate4d(a.w, b.w, c0, c1, c2, c3);
    return r;
}

// Pack 16 f32 -> 16 fp8 (input binarization only)
__device__ __forceinline__ uint4 pack16(const float* f) {
    uint4 r;
    unsigned int* rd = (unsigned int*)&r;
#pragma unroll
    for (int d = 0; d < 4; ++d) {
        int w = __builtin_amdgcn_cvt_pk_fp8_f32(f[4 * d + 0], f[4 * d + 1], 0, false);
        w     = __builtin_amdgcn_cvt_pk_fp8_f32(f[4 * d + 2], f[4 * d + 3], w, true);
        rd[d] = (unsigned int)w;
    }
    return r;
}

// ---------------------------------------------------------------------------
// Kernel 2: fused network, TB=16 rows/block as fp8 e4m3. h = uint4[8192] =
// 128 KB -> 256 blocks = ONE round on 256 CUs.
// R9/R10 lesson: the backend pins this kernel's VGPR budget at 64 regardless
// of waves_per_eu/launch_bounds attributes -> fit in 64 instead. The coef
// register prefetch (cf/cfn, 32 regs) is dropped: coef loads are independent
// of the gathers, issue in parallel with them at phase start, and their L2
// latency hides under 8-deep ILP. Remaining pressure: acc 32 + ij/ijn 16 +
// temps ~12 + addr ~6 ~= 63 <= 64 -> no spill.
// ---------------------------------------------------------------------------
__global__ __launch_bounds__(NTH)
__attribute__((amdgpu_waves_per_eu(4, 4)))
void net_kernel(
    const float*  __restrict__ x,
    const uint2*  __restrict__ coefp,
    const unsigned int* __restrict__ idxp,
    const float*  __restrict__ scaler_w, const float* __restrict__ scaler_b,
    float* __restrict__ out)
{
    __shared__ uint4 h[HIDDEN];             // 128 KB: 16 fp8 rows / neuron
    __shared__ uint4 hx[IN_DIM];            // 16 KB : binarized input
    __shared__ float warr[NWAVES][TB];      // 1 KB
    __shared__ float vals[TB][OUT_DIM];     // 512 B

    const int tid = threadIdx.x;
    const int b0  = blockIdx.x * TB;
    const int g   = tid >> 7;               // output group
    const int t0  = tid & 127;
    const int jb  = g * 1024 + t0;          // neuron base; +128*k

    // Load + binarize input tile (NTH == IN_DIM)
    {
        float v[TB];
#pragma unroll
        for (int r = 0; r < TB; ++r)
            v[r] = (x[(size_t)(b0 + r) * IN_DIM + tid] > 0.5f) ? 1.f : 0.f;
        hx[tid] = pack16(v);                // 0/1 exact in fp8
    }

    unsigned int ij[NPT], ijn[NPT];         // 16 VGPRs
    uint4 acc[NPT];                         // 32 VGPRs

    // Layer 0 indices up-front (overlaps x loads)
#pragma unroll
    for (int k = 0; k < NPT; ++k) ij[k] = idxp[jb + (k << 7)];

    __syncthreads();                        // hx visible

    // Layer 0: prefetch layer-1 idx, gather from hx, write h (disjoint)
#pragma unroll
    for (int k = 0; k < NPT; ++k) ijn[k] = idxp[HIDDEN + jb + (k << 7)];
#pragma unroll
    for (int k = 0; k < NPT; ++k) {
        unsigned int pr = ij[k];
        acc[k] = gate16(hx[pr & 0xffffu], hx[pr >> 16], coefp[jb + (k << 7)]);
    }
#pragma unroll
    for (int k = 0; k < NPT; ++k) h[jb + (k << 7)] = acc[k];
    __syncthreads();

    // Layers 1..4: in-place on h (reads land in regs before writes).
    // coef loaded JIT: independent of gathers, issues alongside them.
    for (int l = 1; l < N_LAYERS - 1; ++l) {
#pragma unroll
        for (int k = 0; k < NPT; ++k) ij[k] = ijn[k];
#pragma unroll
        for (int k = 0; k < NPT; ++k)
            ijn[k] = idxp[(size_t)(l + 1) * HIDDEN + jb + (k << 7)];
        const uint2* cp = coefp + (size_t)l * HIDDEN;
#pragma unroll
        for (int k = 0; k < NPT; ++k) {
            unsigned int pr = ij[k];
            acc[k] = gate16(h[pr & 0xffffu], h[pr >> 16], cp[jb + (k << 7)]);
        }
        __syncthreads();                    // all reads of h done
#pragma unroll
        for (int k = 0; k < NPT; ++k) h[jb + (k << 7)] = acc[k];
        __syncthreads();
    }

    // Layer 5: gate -> accumulate f32 directly (all this thread's neurons are
    // in group g). No pack, no write, no extra barriers, no final rounding.
    float s[TB];
#pragma unroll
    for (int r = 0; r < TB; ++r) s[r] = 0.f;
    {
        const uint2* cp = coefp + (size_t)(N_LAYERS - 1) * HIDDEN;
#pragma unroll
        for (int k = 0; k < NPT; ++k) {
            unsigned int pr = ijn[k];
            uint4 a = h[pr & 0xffffu], b = h[pr >> 16];
            uint2 c = cp[jb + (k << 7)];
            __half2 cp01 = u2h(c.x), cp23 = u2h(c.y);
            float c0 = __low2float(cp01), c1 = __high2float(cp01);
            float c2 = __low2float(cp23), c3 = __high2float(cp23);
            gate4d_acc(a.x, b.x, c0, c1, c2, c3, s + 0);
            gate4d_acc(a.y, b.y, c0, c1, c2, c3, s + 4);
            gate4d_acc(a.z, b.z, c0, c1, c2, c3, s + 8);
            gate4d_acc(a.w, b.w, c0, c1, c2, c3, s + 12);
        }
    }

    // Reduce: 64-lane butterfly (wave = half of group g = wv>>1)
#pragma unroll
    for (int off = 32; off > 0; off >>= 1) {
#pragma unroll
        for (int r = 0; r < TB; ++r) s[r] += __shfl_down(s[r], off);
    }
    if ((tid & 63) == 0) {
        const int wv = tid >> 6;
#pragma unroll
        for (int r = 0; r < TB; ++r) warr[wv][r] = s[r];
    }
    __syncthreads();
    if (tid < TB * OUT_DIM) {               // 128 threads: combine halves
        int r = tid >> 3;
        int k = tid & 7;
        vals[r][k] = (warr[2 * k][r] + warr[2 * k + 1][r]) * INV_TAU;
    }
    __syncthreads();
    if (tid < TB * OUT_DIM) {               // 128 threads: scaler GEMV
        int r = tid >> 3;
        int o = tid & 7;
        float q = scaler_b[o];
#pragma unroll
        for (int k = 0; k < OUT_DIM; ++k)
            q = fmaf(vals[r][k], scaler_w[o * OUT_DIM + k], q);
        out[(size_t)(b0 + r) * OUT_DIM + o] = q;
    }
}

extern "C" void kernel_launch(void* const* d_in, const int* in_sizes, int n_in,
                              void* d_out, int out_size, void* d_ws, size_t ws_size,
                              hipStream_t stream)
{
    const float* x        = (const float*)d_in[0];
    const float* logic_w  = (const float*)d_in[1];
    const float* scaler_w = (const float*)d_in[2];
    const float* scaler_b = (const float*)d_in[3];
    const int*   idx0_a   = (const int*)d_in[4];
    const int*   idx0_b   = (const int*)d_in[5];
    const int*   idx_a    = (const int*)d_in[6];
    const int*   idx_b    = (const int*)d_in[7];
    float* out = (float*)d_out;

    const int n = N_LAYERS * HIDDEN;                 // 49152
    uint2*        coefp = (uint2*)d_ws;              // 384 KB
    unsigned int* idxp  = (unsigned int*)((char*)d_ws + (size_t)n * sizeof(uint2)); // 192 KB

    prep_kernel<<<(n + 255) / 256, 256, 0, stream>>>(logic_w, idx0_a, idx0_b,
                                                     idx_a, idx_b, coefp, idxp, n);
    net_kernel<<<BATCH / TB, NTH, 0, stream>>>(x, coefp, idxp,
                                               scaler_w, scaler_b, out);
}

// Round 12
// 119.629 us; speedup vs baseline: 1.1003x; 1.1003x over previous
//
#include <hip/hip_runtime.h>
#include <hip/hip_fp16.h>

// Problem constants (from reference)
constexpr int BATCH    = 4096;
constexpr int IN_DIM   = 1024;
constexpr int HIDDEN   = 8192;
constexpr int N_LAYERS = 6;
constexpr int OUT_DIM  = 8;
constexpr float INV_TAU = 0.1f;

// Tiling
constexpr int TB   = 8;             // batch rows per workgroup (8 fp8 = uint2)
constexpr int NTH  = 1024;          // threads per block (16 waves)
constexpr int NPT  = HIDDEN / NTH;  // neurons per thread = 8 (one output group)
constexpr int NWAVES = NTH / 64;    // 16

typedef float v2f __attribute__((ext_vector_type(2)));

__device__ __forceinline__ __half2 u2h(unsigned int u) {
    union { unsigned int u; __half2 h; } v; v.u = u; return v.h;
}
__device__ __forceinline__ unsigned int h2u(__half2 h) {
    union { unsigned int u; __half2 h; } v; v.h = h; return v.u;
}
__device__ __forceinline__ uint2 pack4h(float4 v) {
    __half2 lo = __float22half2_rn(make_float2(v.x, v.y));
    __half2 hi = __float22half2_rn(make_float2(v.z, v.w));
    uint2 r; r.x = h2u(lo); r.y = h2u(hi); return r;
}

// ---------------------------------------------------------------------------
// Kernel 1: packed per-neuron records:
//   coefp[l*H+j] = 4 fp16 gate coefs (c0,c1 | c2,c3)
//   idxp [l*H+j] = ia | (ib << 16)
// ---------------------------------------------------------------------------
__global__ void prep_kernel(const float* __restrict__ logic_w,
                            const int* __restrict__ idx0_a,
                            const int* __restrict__ idx0_b,
                            const int* __restrict__ idx_a,
                            const int* __restrict__ idx_b,
                            uint2* __restrict__ coefp,
                            unsigned int* __restrict__ idxp, int n)
{
    int id = blockIdx.x * blockDim.x + threadIdx.x;
    if (id >= n) return;
    const int l = id / HIDDEN;
    const int j = id - l * HIDDEN;

    int ia, ib;
    if (l == 0) { ia = idx0_a[j]; ib = idx0_b[j]; }
    else        { ia = idx_a[(size_t)(l - 1) * HIDDEN + j];
                  ib = idx_b[(size_t)(l - 1) * HIDDEN + j]; }
    idxp[id] = (unsigned int)ia | ((unsigned int)ib << 16);

    const float4* w4 = (const float4*)(logic_w + (size_t)id * 16);
    float4 wa = w4[0], wb = w4[1], wc = w4[2], wd = w4[3];
    float wv[16] = {wa.x, wa.y, wa.z, wa.w, wb.x, wb.y, wb.z, wb.w,
                    wc.x, wc.y, wc.z, wc.w, wd.x, wd.y, wd.z, wd.w};
    float m = wv[0];
#pragma unroll
    for (int i = 1; i < 16; ++i) m = fmaxf(m, wv[i]);
    float e[16];
    float s = 0.f;
#pragma unroll
    for (int i = 0; i < 16; ++i) { e[i] = expf(wv[i] - m); s += e[i]; }
    float inv = 1.f / s;
    const float G0[16] = {0,0,0,0,0,0,0,0, 1,1,1,1,1,1,1,1};
    const float G1[16] = {0,0,1,1,0,0,1,1, -1,-1,0,0,-1,-1,0,0};
    const float G2[16] = {0,0,0,0,1,1,1,1, -1,-1,-1,-1,0,0,0,0};
    const float G3[16] = {0,1,-1,0,-1,0,-2,-1, 1,2,0,1,0,1,-1,0};
    float c0 = 0.f, c1 = 0.f, c2 = 0.f, c3 = 0.f;
#pragma unroll
    for (int i = 0; i < 16; ++i) {
        float p = e[i] * inv;
        c0 = fmaf(p, G0[i], c0);
        c1 = fmaf(p, G1[i], c1);
        c2 = fmaf(p, G2[i], c2);
        c3 = fmaf(p, G3[i], c3);
    }
    coefp[id] = pack4h(make_float4(c0, c1, c2, c3));
}

// gate on ONE dword (4 fp8 rows): convert -> fma -> repack immediately.
__device__ __forceinline__ unsigned int gate4d(unsigned int a8, unsigned int b8,
                                               float c0, float c1, float c2, float c3)
{
    v2f alo = __builtin_amdgcn_cvt_pk_f32_fp8((int)a8, false);
    v2f ahi = __builtin_amdgcn_cvt_pk_f32_fp8((int)a8, true);
    v2f blo = __builtin_amdgcn_cvt_pk_f32_fp8((int)b8, false);
    v2f bhi = __builtin_amdgcn_cvt_pk_f32_fp8((int)b8, true);
    float r0 = fmaf(blo.x, fmaf(c3, alo.x, c2), fmaf(c1, alo.x, c0));
    float r1 = fmaf(blo.y, fmaf(c3, alo.y, c2), fmaf(c1, alo.y, c0));
    float r2 = fmaf(bhi.x, fmaf(c3, ahi.x, c2), fmaf(c1, ahi.x, c0));
    float r3 = fmaf(bhi.y, fmaf(c3, ahi.y, c2), fmaf(c1, ahi.y, c0));
    int w = __builtin_amdgcn_cvt_pk_fp8_f32(r0, r1, 0, false);
    w     = __builtin_amdgcn_cvt_pk_fp8_f32(r2, r3, w, true);
    return (unsigned int)w;
}

// same, but accumulate 4 f32 results (last layer: no repack)
__device__ __forceinline__ void gate4d_acc(unsigned int a8, unsigned int b8,
                                           float c0, float c1, float c2, float c3,
                                           float* s)
{
    v2f alo = __builtin_amdgcn_cvt_pk_f32_fp8((int)a8, false);
    v2f ahi = __builtin_amdgcn_cvt_pk_f32_fp8((int)a8, true);
    v2f blo = __builtin_amdgcn_cvt_pk_f32_fp8((int)b8, false);
    v2f bhi = __builtin_amdgcn_cvt_pk_f32_fp8((int)b8, true);
    s[0] += fmaf(blo.x, fmaf(c3, alo.x, c2), fmaf(c1, alo.x, c0));
    s[1] += fmaf(blo.y, fmaf(c3, alo.y, c2), fmaf(c1, alo.y, c0));
    s[2] += fmaf(bhi.x, fmaf(c3, ahi.x, c2), fmaf(c1, ahi.x, c0));
    s[3] += fmaf(bhi.y, fmaf(c3, ahi.y, c2), fmaf(c1, ahi.y, c0));
}

// gate over 8 fp8 rows (uint2)
__device__ __forceinline__ uint2 gate8d(uint2 a, uint2 b, uint2 c) {
    __half2 cp01 = u2h(c.x), cp23 = u2h(c.y);
    float c0 = __low2float(cp01), c1 = __high2float(cp01);
    float c2 = __low2float(cp23), c3 = __high2float(cp23);
    uint2 r;
    r.x = gate4d(a.x, b.x, c0, c1, c2, c3);
    r.y = gate4d(a.y, b.y, c0, c1, c2, c3);
    return r;
}

// ---------------------------------------------------------------------------
// Kernel 2: fused network, TB=8 rows as fp8 e4m3, LDS PING-PONG:
// hbuf[2][8192] uint2 = 2 x 64 KB. Each layer reads one buffer and writes
// the other -> results written IMMEDIATELY (no acc registers held across a
// hazard -> fits the 64-VGPR budget the backend pins for 1024-thread
// kernels; R8-R11 all spilled 38-43 MB fighting this) and ONE barrier per
// layer instead of two. Thread owns 8 neurons of ONE output group
// (jb = g*1024 + t0 + 128k): last layer accumulates straight into f32 regs.
// ---------------------------------------------------------------------------
__global__ __launch_bounds__(NTH) void net_kernel(
    const float*  __restrict__ x,
    const uint2*  __restrict__ coefp,
    const unsigned int* __restrict__ idxp,
    const float*  __restrict__ scaler_w, const float* __restrict__ scaler_b,
    float* __restrict__ out)
{
    __shared__ uint2 hbuf[2][HIDDEN];       // 128 KB: ping-pong h
    __shared__ uint2 hx[IN_DIM];            // 8 KB  : binarized input
    __shared__ float warr[NWAVES][TB];      // 512 B
    __shared__ float vals[TB][OUT_DIM];     // 256 B

    const int tid = threadIdx.x;
    const int b0  = blockIdx.x * TB;
    const int g   = tid >> 7;               // output group
    const int t0  = tid & 127;
    const int jb  = g * 1024 + t0;          // neuron base; +128*k

    // Load + binarize input tile (NTH == IN_DIM)
    {
        float v[TB];
#pragma unroll
        for (int r = 0; r < TB; ++r)
            v[r] = (x[(size_t)(b0 + r) * IN_DIM + tid] > 0.5f) ? 1.f : 0.f;
        uint2 p;
        int w = __builtin_amdgcn_cvt_pk_fp8_f32(v[0], v[1], 0, false);
        w     = __builtin_amdgcn_cvt_pk_fp8_f32(v[2], v[3], w, true);
        p.x = (unsigned int)w;
        w = __builtin_amdgcn_cvt_pk_fp8_f32(v[4], v[5], 0, false);
        w = __builtin_amdgcn_cvt_pk_fp8_f32(v[6], v[7], w, true);
        p.y = (unsigned int)w;
        hx[tid] = p;                        // 0/1 exact in fp8
    }

    unsigned int ij[NPT], ijn[NPT];         // 16 VGPRs

    // Layer 0 indices up-front (overlaps x loads)
#pragma unroll
    for (int k = 0; k < NPT; ++k) ij[k] = idxp[jb + (k << 7)];

    __syncthreads();                        // hx visible

    // Layer 0: gather hx -> write hbuf[0] immediately (disjoint arrays)
#pragma unroll
    for (int k = 0; k < NPT; ++k) ijn[k] = idxp[HIDDEN + jb + (k << 7)];
#pragma unroll
    for (int k = 0; k < NPT; ++k) {
        unsigned int pr = ij[k];
        hbuf[0][jb + (k << 7)] =
            gate8d(hx[pr & 0xffffu], hx[pr >> 16], coefp[jb + (k << 7)]);
    }
    __syncthreads();

    // Layers 1..4: read hbuf[(l+1)&1], write hbuf[l&1] (disjoint ->
    // immediate writes, single end-of-layer barrier)
    for (int l = 1; l < N_LAYERS - 1; ++l) {
        const int rb = (l + 1) & 1, wb = l & 1;
#pragma unroll
        for (int k = 0; k < NPT; ++k) ij[k] = ijn[k];
#pragma unroll
        for (int k = 0; k < NPT; ++k)
            ijn[k] = idxp[(size_t)(l + 1) * HIDDEN + jb + (k << 7)];
        const uint2* cp = coefp + (size_t)l * HIDDEN;
#pragma unroll
        for (int k = 0; k < NPT; ++k) {
            unsigned int pr = ij[k];
            hbuf[wb][jb + (k << 7)] =
                gate8d(hbuf[rb][pr & 0xffffu], hbuf[rb][pr >> 16], cp[jb + (k << 7)]);
        }
        __syncthreads();
    }

    // Layer 5: read hbuf[0] (layer 4 wrote l&1 = 0), accumulate f32 directly.
    float s[TB];
#pragma unroll
    for (int r = 0; r < TB; ++r) s[r] = 0.f;
    {
        const uint2* cp = coefp + (size_t)(N_LAYERS - 1) * HIDDEN;
#pragma unroll
        for (int k = 0; k < NPT; ++k) {
            unsigned int pr = ijn[k];
            uint2 a = hbuf[0][pr & 0xffffu], b = hbuf[0][pr >> 16];
            uint2 c = cp[jb + (k << 7)];
            __half2 cp01 = u2h(c.x), cp23 = u2h(c.y);
            float c0 = __low2float(cp01), c1 = __high2float(cp01);
            float c2 = __low2float(cp23), c3 = __high2float(cp23);
            gate4d_acc(a.x, b.x, c0, c1, c2, c3, s + 0);
            gate4d_acc(a.y, b.y, c0, c1, c2, c3, s + 4);
        }
    }

    // Reduce: 64-lane butterfly (wave = half of group g = wv>>1)
#pragma unroll
    for (int off = 32; off > 0; off >>= 1) {
#pragma unroll
        for (int r = 0; r < TB; ++r) s[r] += __shfl_down(s[r], off);
    }
    if ((tid & 63) == 0) {
        const int wv = tid >> 6;
#pragma unroll
        for (int r = 0; r < TB; ++r) warr[wv][r] = s[r];
    }
    __syncthreads();
    if (tid < TB * OUT_DIM) {               // 64 threads: combine halves
        int r = tid >> 3;
        int k = tid & 7;
        vals[r][k] = (warr[2 * k][r] + warr[2 * k + 1][r]) * INV_TAU;
    }
    __syncthreads();
    if (tid < TB * OUT_DIM) {               // 64 threads: scaler GEMV
        int r = tid >> 3;
        int o = tid & 7;
        float q = scaler_b[o];
#pragma unroll
        for (int k = 0; k < OUT_DIM; ++k)
            q = fmaf(vals[r][k], scaler_w[o * OUT_DIM + k], q);
        out[(size_t)(b0 + r) * OUT_DIM + o] = q;
    }
}

extern "C" void kernel_launch(void* const* d_in, const int* in_sizes, int n_in,
                              void* d_out, int out_size, void* d_ws, size_t ws_size,
                              hipStream_t stream)
{
    const float* x        = (const float*)d_in[0];
    const float* logic_w  = (const float*)d_in[1];
    const float* scaler_w = (const float*)d_in[2];
    const float* scaler_b = (const float*)d_in[3];
    const int*   idx0_a   = (const int*)d_in[4];
    const int*   idx0_b   = (const int*)d_in[5];
    const int*   idx_a    = (const int*)d_in[6];
    const int*   idx_b    = (const int*)d_in[7];
    float* out = (float*)d_out;

    const int n = N_LAYERS * HIDDEN;                 // 49152
    uint2*        coefp = (uint2*)d_ws;              // 384 KB
    unsigned int* idxp  = (unsigned int*)((char*)d_ws + (size_t)n * sizeof(uint2)); // 192 KB

    prep_kernel<<<(n + 255) / 256, 256, 0, stream>>>(logic_w, idx0_a, idx0_b,
                                                     idx_a, idx_b, coefp, idxp, n);
    net_kernel<<<BATCH / TB, NTH, 0, stream>>>(x, coefp, idxp,
                                               scaler_w, scaler_b, out);
}